// Round 9
// baseline (836.835 us; speedup 1.0000x reference)
//
#include <hip/hip_runtime.h>
#include <hip/hip_fp16.h>

#define B_ 16
#define T_ 256
#define D_ 128
#define H_ 256

typedef _Float16 f16;
typedef __attribute__((ext_vector_type(2))) _Float16 f16x2;
typedef __attribute__((ext_vector_type(4))) int i32x4;

__device__ __forceinline__ float fast_rcp(float x) {
#if __has_builtin(__builtin_amdgcn_rcpf)
    return __builtin_amdgcn_rcpf(x);
#else
    return 1.0f / x;
#endif
}
__device__ __forceinline__ float sigmoid_f(float x) {
    return fast_rcp(1.0f + __expf(-x));
}
__device__ __forceinline__ float tanh_f(float x) {
    float e = __expf(2.0f * x);
    return 1.0f - 2.0f * fast_rcp(1.0f + e);
}

// ---- weight prep: Whh f32 [768][256] -> i8, k-PERMUTED packing + row scales ----
// w8[r*64 + i] bytes {0,1,2,3} = rint(127/rowmax * W[r][{i, 64+i, 128+i, 192+i}])
// (matches sh_h8 dword i = packed h units {i, 64+i, 128+i, 192+i})
__global__ __launch_bounds__(256) void k_wprep8(const float* __restrict__ wa,
                                                const float* __restrict__ wb,
                                                int* __restrict__ w8a, int* __restrict__ w8b,
                                                float* __restrict__ sca, float* __restrict__ scb) {
    int row_id = blockIdx.x * 4 + (threadIdx.x >> 6); // [0,1536)
    int l = threadIdx.x & 63;
    const float* W = row_id < 768 ? wa : wb;
    int* w8 = row_id < 768 ? w8a : w8b;
    float* sc = row_id < 768 ? sca : scb;
    int r = row_id & 767;
    const float* Wr = W + r * 256;
    float v0 = Wr[l], v1 = Wr[64 + l], v2 = Wr[128 + l], v3 = Wr[192 + l];
    float m = fmaxf(fmaxf(fabsf(v0), fabsf(v1)), fmaxf(fabsf(v2), fabsf(v3)));
#pragma unroll
    for (int d = 1; d < 64; d <<= 1) m = fmaxf(m, __shfl_xor(m, d));
    float qs = m > 0.f ? 127.f / m : 0.f;
    if (l == 0) sc[r] = m / (127.f * 127.f);
    int q0 = (int)rintf(v0 * qs) & 255;
    int q1 = (int)rintf(v1 * qs) & 255;
    int q2 = (int)rintf(v2 * qs) & 255;
    int q3 = (int)rintf(v3 * qs) & 255;
    w8[r * 64 + l] = q0 | (q1 << 8) | (q2 << 16) | (q3 << 24);
}

// ---- mask precompute: pos[b][s] = first t with targets[b,t]==s (else T) ----
__global__ void k_pos_init(int* __restrict__ pos) {
    pos[blockIdx.x * 256 + threadIdx.x] = T_;
}
__global__ void k_pos_scan(const int* __restrict__ tgt, int* __restrict__ pos) {
    int i = blockIdx.x * 256 + threadIdx.x;
    int b = i >> 8, t = i & 255;
    int s = tgt[i] & 255;
    atomicMin(&pos[(b << 8) + s], t);
}

// ---- enc_in = inputs @ W_enc^T + b_enc ----
__global__ __launch_bounds__(256) void k_encA(const float* __restrict__ in,
                                              const float* __restrict__ W,
                                              const float* __restrict__ bias,
                                              float* __restrict__ out) {
    int bt0 = blockIdx.x * 8;
    int a = threadIdx.x;
    float bv = bias[a];
    float acc[8];
#pragma unroll
    for (int tt = 0; tt < 8; ++tt) acc[tt] = bv;
    const float* wr = W + a * D_;
    for (int k = 0; k < D_; k += 4) {
        float4 w4 = *(const float4*)(wr + k);
#pragma unroll
        for (int tt = 0; tt < 8; ++tt) {
            float4 x4 = *(const float4*)(in + (bt0 + tt) * D_ + k);
            acc[tt] += w4.x * x4.x + w4.y * x4.y + w4.z * x4.z + w4.w * x4.w;
        }
    }
#pragma unroll
    for (int tt = 0; tt < 8; ++tt) out[(bt0 + tt) * H_ + a] = acc[tt];
}

// ---- x_proj: giA[(bt)*256+j] = f16x2{gi_r+bih_r+bhh_r, gi_z+bih_z+bhh_z};
//      giB = f16{gi_n+bih_n}; optional teacher-forcing row gather ----
__global__ __launch_bounds__(256) void k_proj3(const float* __restrict__ in,
                                               const float* __restrict__ W,
                                               const float* __restrict__ bih,
                                               const float* __restrict__ bhh,
                                               const int* __restrict__ tgt,
                                               f16x2* __restrict__ giA,
                                               f16* __restrict__ giB) {
    int bt0 = blockIdx.x * 8;
    int b = bt0 >> 8;
    int a = threadIdx.x;
    const float* rp[8];
#pragma unroll
    for (int tt = 0; tt < 8; ++tt) {
        int t = (bt0 & 255) + tt;
        int tsrc = t;
        if (tgt) tsrc = tgt[(b << 8) + ((t + 255) & 255)] & 255; // roll(targets,1)
        rp[tt] = in + ((b << 8) + tsrc) * H_;
    }
    float acc0[8], acc1[8], acc2[8];
    float b0 = bih[a] + bhh[a];
    float b1 = bih[a + 256] + bhh[a + 256];
    float b2 = bih[a + 512];
#pragma unroll
    for (int tt = 0; tt < 8; ++tt) { acc0[tt] = b0; acc1[tt] = b1; acc2[tt] = b2; }
    const float* w0 = W + a * H_;
    const float* w1 = W + (a + 256) * H_;
    const float* w2 = W + (a + 512) * H_;
    for (int k = 0; k < H_; k += 4) {
        float4 a4 = *(const float4*)(w0 + k);
        float4 b4 = *(const float4*)(w1 + k);
        float4 c4 = *(const float4*)(w2 + k);
#pragma unroll
        for (int tt = 0; tt < 8; ++tt) {
            float4 x4 = *(const float4*)(rp[tt] + k);
            acc0[tt] += a4.x * x4.x + a4.y * x4.y + a4.z * x4.z + a4.w * x4.w;
            acc1[tt] += b4.x * x4.x + b4.y * x4.y + b4.z * x4.z + b4.w * x4.w;
            acc2[tt] += c4.x * x4.x + c4.y * x4.y + c4.z * x4.z + c4.w * x4.w;
        }
    }
#pragma unroll
    for (int tt = 0; tt < 8; ++tt) {
        int row = bt0 + tt;
        giA[row * 256 + a] = (f16x2){(f16)acc0[tt], (f16)acc1[tt]};
        giB[row * 256 + a] = (f16)acc2[tt];
    }
}

// ---- single-row projection (q / k), no bias ----
__global__ __launch_bounds__(256) void k_proj1(const float* __restrict__ in,
                                               const float* __restrict__ W,
                                               float* __restrict__ out) {
    int bt0 = blockIdx.x * 8;
    int a = threadIdx.x;
    float acc[8];
#pragma unroll
    for (int tt = 0; tt < 8; ++tt) acc[tt] = 0.f;
    const float* w0 = W + a * H_;
    for (int k = 0; k < H_; k += 4) {
        float4 w4 = *(const float4*)(w0 + k);
#pragma unroll
        for (int tt = 0; tt < 8; ++tt) {
            float4 x4 = *(const float4*)(in + (bt0 + tt) * H_ + k);
            acc[tt] += w4.x * x4.x + w4.y * x4.y + w4.z * x4.z + w4.w * x4.w;
        }
    }
#pragma unroll
    for (int tt = 0; tt < 8; ++tt) out[(bt0 + tt) * H_ + a] = acc[tt];
}

// ---- fused GRU (enc then dec), 16 blocks x 768 threads: one CU per batch ----
// Thread tid = gate row (g=tid>>8, j=tid&255), full K=256 in-thread via 64
// v_dot4_i32_i8. h-broadcast WITHOUT per-thread LDS streams (R8's ~1000
// cyc/step LDS cost): h is wave-uniform, so each wave does ONE ds_read_b32
// (lane l -> packed h dword l), then v_readlane -> SGPR feeds the dot as its
// scalar operand (VOP3P: 1 SGPR src legal). LDS instrs/step/CU: 192 -> ~16.
// Weights: 64 dwords via asm volatile global_load (un-sinkable) consumed by
// asm dot with "v" constraint (def+use both demand arch VGPR -> no AGPR
// round-trip, R8's other tax). 4 rotating accs break the dot dep chain.
// Gates centralized on tid<256 (idle waves cost less than redundant VALU).
__global__ __launch_bounds__(768)
__attribute__((amdgpu_waves_per_eu(3, 3)))
void k_gru2(const int* __restrict__ w8e, const int* __restrict__ w8d,
            const float* __restrict__ sce, const float* __restrict__ scd,
            const f16x2* __restrict__ giAe, const f16* __restrict__ giBe,
            const f16x2* __restrict__ giAd, const f16* __restrict__ giBd,
            const float* __restrict__ bhhe, const float* __restrict__ bhhd,
            float* __restrict__ enc_out, float* __restrict__ dec_out) {
    __shared__ __align__(16) int sh_h8[64];   // h i8: dword i = units {i,64+i,128+i,192+i}
    __shared__ float sh_gh[768];
    const int tid = threadIdx.x;
    const int m = blockIdx.x;                 // batch
    const int j = tid & 255;                  // unit (column)
    const int lane = tid & 63;

    if (tid < 64) sh_h8[tid] = 0;
    float hj = 0.f;                           // gate threads' h_prev (exact f32)
    __syncthreads();

    for (int ph = 0; ph < 2; ++ph) {
        const int* w8 = ph ? w8d : w8e;
        const float sc = (ph ? scd : sce)[tid];
        const float bn = (ph ? bhhd : bhhe)[512 + j];
        const f16x2* gA = (ph ? giAd : giAe) + m * (T_ * 256);
        const f16* gB = (ph ? giBd : giBe) + m * (T_ * 256);
        float* outp = (ph ? dec_out : enc_out) + m * (T_ * H_);

        // weights: volatile asm loads (cannot be sunk back into the loop)
        i32x4 wq[16];
        {
            unsigned long long base = (unsigned long long)(w8 + tid * 64);
#pragma unroll
            for (int i = 0; i < 16; ++i)
                asm volatile("global_load_dwordx4 %0, %1, off offset:%2"
                             : "=v"(wq[i]) : "v"(base), "i"(i * 16));
            asm volatile("s_waitcnt vmcnt(0)" ::: "memory");
        }

        for (int t = 0; t < T_; ++t) {
            // own packed-h dword (identical content in every wave)
            int hreg = sh_h8[lane];
            // gi loads issued early; in flight during the dot phase
            f16x2 gab = {0, 0};
            f16 gn = 0;
            if (tid < 256) {
                gab = gA[t * 256 + j];
                gn = gB[t * 256 + j];
            }

            int acc[4] = {0, 0, 0, 0};
#pragma unroll
            for (int i = 0; i < 64; ++i) {
                int hs = __builtin_amdgcn_readlane(hreg, i);
                asm("v_dot4_i32_i8 %0, %1, %2, %0"
                    : "+v"(acc[i & 3])
                    : "v"(wq[i >> 2][i & 3]), "s"(hs));
            }
            sh_gh[tid] = (float)((acc[0] + acc[1]) + (acc[2] + acc[3])) * sc;
            asm volatile("s_waitcnt lgkmcnt(0)" ::: "memory");
            __builtin_amdgcn_s_barrier();

            if (tid < 256) {
                float ghr = sh_gh[j], ghz = sh_gh[256 + j], ghn = sh_gh[512 + j];
                float rr = sigmoid_f((float)gab[0] + ghr);
                float zz = sigmoid_f((float)gab[1] + ghz);
                float nv = tanh_f((float)gn + rr * (ghn + bn));
                float hn = (1.f - zz) * nv + zz * hj;
                hj = hn;
                outp[t * H_ + j] = hn;
                // byte (j>>6) of dword (j&63): conflict-free within each wave
                ((char*)sh_h8)[(j & 63) * 4 + (j >> 6)] = (char)(int)rintf(hn * 127.f);
            }
            asm volatile("s_waitcnt lgkmcnt(0)" ::: "memory");
            __builtin_amdgcn_s_barrier();
        }
    }
}

// ---- transpose k[b][s][a] -> kT[b][a][s] ----
__global__ __launch_bounds__(256) void k_transpose(const float* __restrict__ k_,
                                                   float* __restrict__ kT) {
    __shared__ float tile[64][65];
    int blk = blockIdx.x;
    int b = blk >> 4;
    int ti = (blk >> 2) & 3;
    int tj = blk & 3;
    int lane = threadIdx.x & 63;
    int ty = threadIdx.x >> 6;
    const float* kb = k_ + b * (T_ * H_);
    for (int r = ty; r < 64; r += 4)
        tile[r][lane] = kb[(ti * 64 + r) * H_ + tj * 64 + lane];
    __syncthreads();
    float* kTb = kT + b * (T_ * H_);
    for (int r = ty; r < 64; r += 4)
        kTb[(tj * 64 + r) * T_ + ti * 64 + lane] = tile[lane][r];
}

// ---- logits[b,t,s] = mask ? v . tanh(q[b,t,:]+k[b,s,:]) : -1e9 ----
__global__ __launch_bounds__(256) void k_scores(const float* __restrict__ q,
                                                const float* __restrict__ kT,
                                                const float* __restrict__ v,
                                                const int* __restrict__ pos,
                                                float* __restrict__ out) {
    __shared__ float sq[4][256];
    __shared__ float sv[256];
    int blk = blockIdx.x;
    int b = blk >> 6;
    int t0 = (blk & 63) * 4;
    int s = threadIdx.x;
    sv[s] = v[s];
#pragma unroll
    for (int tt = 0; tt < 4; ++tt)
        sq[tt][s] = q[((b << 8) + t0 + tt) * H_ + s];
    __syncthreads();
    int ps = pos[(b << 8) + s];
    float acc[4] = {0.f, 0.f, 0.f, 0.f};
    const float* kTb = kT + b * (T_ * H_);
    for (int a = 0; a < H_; ++a) {
        float kv = kTb[a * T_ + s];
        float va = sv[a];
#pragma unroll
        for (int tt = 0; tt < 4; ++tt) {
            float th = tanh_f(sq[tt][a] + kv);
            acc[tt] += va * th;
        }
    }
#pragma unroll
    for (int tt = 0; tt < 4; ++tt) {
        int t = t0 + tt;
        out[((b << 8) + t) * T_ + s] = (t <= ps) ? acc[tt] : -1.0e9f;
    }
}

extern "C" void kernel_launch(void* const* d_in, const int* in_sizes, int n_in,
                              void* d_out, int out_size, void* d_ws, size_t ws_size,
                              hipStream_t stream) {
    (void)in_sizes; (void)n_in; (void)out_size; (void)ws_size;
    const float* inputs   = (const float*)d_in[0];
    const int* targets    = (const int*)d_in[1];
    const float* W_enc   = (const float*)d_in[2];
    const float* b_enc   = (const float*)d_in[3];
    const float* enc_Wih = (const float*)d_in[4];
    const float* enc_Whh = (const float*)d_in[5];
    const float* enc_bih = (const float*)d_in[6];
    const float* enc_bhh = (const float*)d_in[7];
    const float* dec_Wih = (const float*)d_in[8];
    const float* dec_Whh = (const float*)d_in[9];
    const float* dec_bih = (const float*)d_in[10];
    const float* dec_bhh = (const float*)d_in[11];
    const float* Wq = (const float*)d_in[12];
    const float* Wk = (const float*)d_in[13];
    const float* v  = (const float*)d_in[14];
    float* out = (float*)d_out;

    float* ws = (float*)d_ws;
    float* enc_in   = ws;                        // 1,048,576 f
    f16x2* giAe     = (f16x2*)(ws + 1048576);    // 1,048,576 f
    f16*   giBe     = (f16*)(ws + 2097152);      // 524,288 f
    f16x2* giAd     = (f16x2*)(ws + 2621440);    // 1,048,576 f
    f16*   giBd     = (f16*)(ws + 3670016);      // 524,288 f
    float* enc_out  = ws + 4194304;              // 1,048,576 f
    float* dec_out  = ws + 5242880;              // 1,048,576 f
    int*   w8e      = (int*)(ws + 6291456);      // 49,152 dw
    int*   w8d      = (int*)(ws + 6340608);      // 49,152 dw
    float* sce      = ws + 6389760;              // 768
    float* scd      = ws + 6390528;              // 768
    int*   pos      = (int*)(ws + 6391296);      // 4,096
    float* q  = enc_in;           // alias: enc_in dead after the two proj3
    float* kk = (float*)giAe;     // alias: gi dead after gru
    float* kT = (float*)giAd;     // alias

    k_wprep8<<<384, 256, 0, stream>>>(enc_Whh, dec_Whh, w8e, w8d, sce, scd);
    k_pos_init<<<16, 256, 0, stream>>>(pos);
    k_pos_scan<<<16, 256, 0, stream>>>(targets, pos);
    k_encA<<<512, 256, 0, stream>>>(inputs, W_enc, b_enc, enc_in);
    k_proj3<<<512, 256, 0, stream>>>(enc_in, enc_Wih, enc_bih, enc_bhh, nullptr, giAe, giBe);
    k_proj3<<<512, 256, 0, stream>>>(enc_in, dec_Wih, dec_bih, dec_bhh, targets, giAd, giBd);
    k_gru2<<<16, 768, 0, stream>>>(w8e, w8d, sce, scd, giAe, giBe, giAd, giBd,
                                   enc_bhh, dec_bhh, enc_out, dec_out);
    k_proj1<<<512, 256, 0, stream>>>(dec_out, Wq, q);
    k_proj1<<<512, 256, 0, stream>>>(enc_out, Wk, kk);
    k_transpose<<<256, 256, 0, stream>>>(kk, kT);
    k_scores<<<1024, 256, 0, stream>>>(q, kT, v, pos, out);
}

// Round 10
// 705.549 us; speedup vs baseline: 1.1861x; 1.1861x over previous
//
#include <hip/hip_runtime.h>
#include <hip/hip_fp16.h>

#define B_ 16
#define T_ 256
#define D_ 128
#define H_ 256

typedef _Float16 f16;
typedef __attribute__((ext_vector_type(2))) _Float16 f16x2;
typedef __attribute__((ext_vector_type(4))) int i32x4;

__device__ __forceinline__ float fast_rcp(float x) {
#if __has_builtin(__builtin_amdgcn_rcpf)
    return __builtin_amdgcn_rcpf(x);
#else
    return 1.0f / x;
#endif
}
__device__ __forceinline__ float sigmoid_f(float x) {
    return fast_rcp(1.0f + __expf(-x));
}
__device__ __forceinline__ float tanh_f(float x) {
    float e = __expf(2.0f * x);
    return 1.0f - 2.0f * fast_rcp(1.0f + e);
}
__device__ __forceinline__ int dot4(int a, int b, int c) {
#if __has_builtin(__builtin_amdgcn_sdot4)
    return __builtin_amdgcn_sdot4(a, b, c, false);
#else
    int d;
    asm("v_dot4_i32_i8 %0, %1, %2, %3" : "=v"(d) : "v"(a), "v"(b), "v"(c));
    return d;
#endif
}

// ---- weight prep: Whh f32 [768][256] -> i8 packed for the (j,hf) GRU layout ----
// dst dword [((j*2+hf)*3+g)*32 + i] bytes b=0..3 = rint(127/rowmax * W[g*256+j][hf*128 + i + 32b])
// sc[r] = rowmax/(127*127). One wave per row; lane l: hf=l>>5, i=l&31.
__global__ __launch_bounds__(256) void k_wprep8(const float* __restrict__ wa,
                                                const float* __restrict__ wb,
                                                int* __restrict__ w8a, int* __restrict__ w8b,
                                                float* __restrict__ sca, float* __restrict__ scb) {
    int wid = blockIdx.x * 4 + (threadIdx.x >> 6); // [0,1536)
    int l = threadIdx.x & 63;
    const float* W = wid < 768 ? wa : wb;
    int* w8 = wid < 768 ? w8a : w8b;
    float* sc = wid < 768 ? sca : scb;
    int r = wid & 767;
    int hf = l >> 5, i = l & 31;
    const float* Wr = W + r * 256 + hf * 128 + i;
    float v0 = Wr[0], v1 = Wr[32], v2 = Wr[64], v3 = Wr[96];
    float m = fmaxf(fmaxf(fabsf(v0), fabsf(v1)), fmaxf(fabsf(v2), fabsf(v3)));
#pragma unroll
    for (int d = 1; d < 64; d <<= 1) m = fmaxf(m, __shfl_xor(m, d));
    float qs = m > 0.f ? 127.f / m : 0.f;
    if (l == 0) sc[r] = m / (127.f * 127.f);
    int q0 = (int)rintf(v0 * qs) & 255;
    int q1 = (int)rintf(v1 * qs) & 255;
    int q2 = (int)rintf(v2 * qs) & 255;
    int q3 = (int)rintf(v3 * qs) & 255;
    int j = r & 255, g = r >> 8;
    w8[((j * 2 + hf) * 3 + g) * 32 + i] = q0 | (q1 << 8) | (q2 << 16) | (q3 << 24);
}

// ---- mask precompute, fused: pos[b][s] = first t with targets[b,t]==s (else T) ----
__global__ void k_pos(const int* __restrict__ tgt, int* __restrict__ pos) {
    __shared__ int pl[256];
    int b = blockIdx.x, tid = threadIdx.x;
    pl[tid] = T_;
    __syncthreads();
    atomicMin(&pl[tgt[b * 256 + tid] & 255], tid);
    __syncthreads();
    pos[b * 256 + tid] = pl[tid];
}

// ---- fused encoder-linear + x_proj -> f16 (bhh folded into r,z gates) ----
// Per block: 8 source rows. Stage inputs rows -> LDS; compute enc rows (inputs@Wenc^T
// + benc) -> LDS; then project with Wih. enc_in never materialized in HBM.
__global__ __launch_bounds__(256) void k_proj3(const float* __restrict__ inputs,
                                               const float* __restrict__ Wenc,
                                               const float* __restrict__ benc,
                                               const float* __restrict__ W,
                                               const float* __restrict__ bih,
                                               const float* __restrict__ bhh,
                                               const int* __restrict__ tgt,
                                               f16x2* __restrict__ giA,
                                               f16* __restrict__ giB) {
    __shared__ float s_in[8][128];
    __shared__ float s_enc[8][256];
    int bt0 = blockIdx.x * 8;
    int b = bt0 >> 8;
    int a = threadIdx.x;
    int tsrc[8];
#pragma unroll
    for (int tt = 0; tt < 8; ++tt) {
        int t = (bt0 & 255) + tt;
        tsrc[tt] = tgt ? (tgt[(b << 8) + ((t + 255) & 255)] & 255) : t; // roll(targets,1)
    }
    // stage the 8 input rows (1024 floats, 4 per thread)
    {
        int idx = a * 4, row = idx >> 7, k = idx & 127;
        *(float4*)&s_in[row][k] = *(const float4*)(inputs + (b * 256 + tsrc[row]) * 128 + k);
    }
    __syncthreads();
    // enc rows: thread a computes column a of all 8 rows
    float eacc[8];
#pragma unroll
    for (int tt = 0; tt < 8; ++tt) eacc[tt] = benc[a];
    const float* wr = Wenc + a * 128;
    for (int k = 0; k < 128; k += 4) {
        float4 w4 = *(const float4*)(wr + k);
#pragma unroll
        for (int tt = 0; tt < 8; ++tt) {
            float4 x4 = *(const float4*)&s_in[tt][k];
            eacc[tt] += w4.x * x4.x + w4.y * x4.y + w4.z * x4.z + w4.w * x4.w;
        }
    }
#pragma unroll
    for (int tt = 0; tt < 8; ++tt) s_enc[tt][a] = eacc[tt];
    __syncthreads();
    // project with Wih (rows a, a+256, a+512)
    float acc0[8], acc1[8], acc2[8];
    float b0 = bih[a] + bhh[a];
    float b1 = bih[a + 256] + bhh[a + 256];
    float b2 = bih[a + 512];
#pragma unroll
    for (int tt = 0; tt < 8; ++tt) { acc0[tt] = b0; acc1[tt] = b1; acc2[tt] = b2; }
    const float* w0 = W + a * H_;
    const float* w1 = W + (a + 256) * H_;
    const float* w2 = W + (a + 512) * H_;
    for (int k = 0; k < H_; k += 4) {
        float4 a4 = *(const float4*)(w0 + k);
        float4 b4 = *(const float4*)(w1 + k);
        float4 c4 = *(const float4*)(w2 + k);
#pragma unroll
        for (int tt = 0; tt < 8; ++tt) {
            float4 x4 = *(const float4*)&s_enc[tt][k];
            acc0[tt] += a4.x * x4.x + a4.y * x4.y + a4.z * x4.z + a4.w * x4.w;
            acc1[tt] += b4.x * x4.x + b4.y * x4.y + b4.z * x4.z + b4.w * x4.w;
            acc2[tt] += c4.x * x4.x + c4.y * x4.y + c4.z * x4.z + c4.w * x4.w;
        }
    }
#pragma unroll
    for (int tt = 0; tt < 8; ++tt) {
        int row = bt0 + tt;
        giA[row * 256 + a] = (f16x2){(f16)acc0[tt], (f16)acc1[tt]};
        giB[row * 256 + a] = (f16)acc2[tt];
    }
}

// ---- fused GRU (enc then dec), 16 blocks x 512 threads: one CU per batch ----
// Thread = (unit j = tid>>1, K-half hf = tid&1). Per thread: 3 gate rows x
// half-K = 96 weight dwords (24 asm-volatile dwordx4) -> total VGPR pressure
// ~125, INSIDE the ~128 budget the allocator targets, so no AGPR round-trip
// (the R8/R9 2x tax) and no sinking (asm volatile). Gates lane-local after one
// shfl_xor(1) half-combine -> no sh_gh exchange; ONE barrier/step with
// double-buffered 512B h ping-pong; h-broadcast = 8 ds_read_b128/thread at 2
// wave-addresses (2-way = free).
__global__ __launch_bounds__(512)
__attribute__((amdgpu_waves_per_eu(2, 2)))
void k_gru2(const int* __restrict__ w8e, const int* __restrict__ w8d,
            const float* __restrict__ sce, const float* __restrict__ scd,
            const f16x2* __restrict__ giAe, const f16* __restrict__ giBe,
            const f16x2* __restrict__ giAd, const f16* __restrict__ giBd,
            const float* __restrict__ bhhe, const float* __restrict__ bhhd,
            float* __restrict__ enc_out, float* __restrict__ dec_out) {
    __shared__ __align__(16) int sh_h8[2][64];  // dword hf*32+i packs h units {hf*128+i+32b}
    const int tid = threadIdx.x;
    const int m = blockIdx.x;
    const int j = tid >> 1;
    const int hf = tid & 1;

    if (tid < 128) ((int*)sh_h8)[tid] = 0;
    float hj = 0.f;
    __syncthreads();

    for (int ph = 0; ph < 2; ++ph) {
        const int* w8 = ph ? w8d : w8e;
        const float* scp = ph ? scd : sce;
        const float sc0 = scp[j], sc1 = scp[256 + j], sc2 = scp[512 + j];
        const float bn = (ph ? bhhd : bhhe)[512 + j];
        const f16x2* gA = (ph ? giAd : giAe) + m * (T_ * 256);
        const f16* gB = (ph ? giBd : giBe) + m * (T_ * 256);
        float* outp = (ph ? dec_out : enc_out) + m * (T_ * H_);

        // 96 weight dwords -> arch VGPRs (volatile asm: un-sinkable)
        i32x4 wq[3][8];
        {
            unsigned long long base = (unsigned long long)(w8 + tid * 96);
#pragma unroll
            for (int g = 0; g < 3; ++g)
#pragma unroll
                for (int i4 = 0; i4 < 8; ++i4)
                    asm volatile("global_load_dwordx4 %0, %1, off offset:%2"
                                 : "=v"(wq[g][i4]) : "v"(base), "i"(g * 128 + i4 * 16));
            asm volatile("s_waitcnt vmcnt(0)" ::: "memory");
        }

        f16x2 gab = gA[j];
        f16 gn = gB[j];

        for (int t = 0; t < T_; ++t) {
            const int cur = t & 1;
            int a0 = 0, a1 = 0, a2 = 0;
            const i32x4* hb = (const i32x4*)((const char*)sh_h8 + cur * 256 + hf * 128);
#pragma unroll
            for (int i4 = 0; i4 < 8; ++i4) {
                i32x4 h4 = hb[i4];
#pragma unroll
                for (int d = 0; d < 4; ++d) {
                    a0 = dot4(wq[0][i4][d], h4[d], a0);
                    a1 = dot4(wq[1][i4][d], h4[d], a1);
                    a2 = dot4(wq[2][i4][d], h4[d], a2);
                }
            }
            // prefetch next step's gi (in flight across gates + barrier)
            f16x2 ngab = {0, 0};
            f16 ngn = 0;
            const bool pf = (t < T_ - 1);
            if (pf) {
                ngab = gA[(t + 1) * 256 + j];
                ngn = gB[(t + 1) * 256 + j];
            }
            // cross-half combine (lane pair) + scale
            float p0 = (float)(a0 + __shfl_xor(a0, 1)) * sc0;
            float p1 = (float)(a1 + __shfl_xor(a1, 1)) * sc1;
            float p2 = (float)(a2 + __shfl_xor(a2, 1)) * sc2;

            float rr = sigmoid_f((float)gab[0] + p0);
            float zz = sigmoid_f((float)gab[1] + p1);
            float nv = tanh_f((float)gn + rr * (p2 + bn));
            float hn = (1.f - zz) * nv + zz * hj;
            hj = hn;

            if (hf) {
                outp[t * H_ + j] = hn;   // odd lanes: output store
            } else {                      // even lanes: h byte into next buffer
                ((char*)sh_h8)[(cur ^ 1) * 256 + (j >> 7) * 128 + (j & 31) * 4 + ((j >> 5) & 3)]
                    = (char)(int)rintf(hn * 127.f);
            }
            gab = ngab; gn = ngn;
            if (!pf) { gab = gA[t * 256 + j]; gn = gB[t * 256 + j]; } // dead reload, keeps types simple
            // LDS-only barrier: gi loads + out stores stay in flight
            asm volatile("s_waitcnt lgkmcnt(0)" ::: "memory");
            __builtin_amdgcn_s_barrier();
        }
    }
}

// ---- q = dec_out@Wq^T ; kT[b][a][s] = (enc_out@Wk^T)^T  (one kernel, 1024 blocks) ----
__global__ __launch_bounds__(256) void k_qk(const float* __restrict__ dec_out,
                                            const float* __restrict__ Wq,
                                            const float* __restrict__ enc_out,
                                            const float* __restrict__ Wk,
                                            float* __restrict__ q,
                                            float* __restrict__ kT) {
    __shared__ float tile[8][256];
    int blk = blockIdx.x;
    bool isq = blk < 512;
    int bt0 = (isq ? blk : blk - 512) * 8;
    const float* in = isq ? dec_out : enc_out;
    const float* W = isq ? Wq : Wk;
    int a = threadIdx.x;
    float acc[8];
#pragma unroll
    for (int tt = 0; tt < 8; ++tt) acc[tt] = 0.f;
    const float* w0 = W + a * H_;
    for (int k = 0; k < H_; k += 4) {
        float4 w4 = *(const float4*)(w0 + k);
#pragma unroll
        for (int tt = 0; tt < 8; ++tt) {
            float4 x4 = *(const float4*)(in + (bt0 + tt) * H_ + k);
            acc[tt] += w4.x * x4.x + w4.y * x4.y + w4.z * x4.z + w4.w * x4.w;
        }
    }
    if (isq) {
#pragma unroll
        for (int tt = 0; tt < 8; ++tt) q[(bt0 + tt) * H_ + a] = acc[tt];
    } else {
#pragma unroll
        for (int tt = 0; tt < 8; ++tt) tile[tt][a] = acc[tt];
        __syncthreads();
        int b = bt0 >> 8, s0 = bt0 & 255;
        float4 f0 = {tile[0][a], tile[1][a], tile[2][a], tile[3][a]};
        float4 f1 = {tile[4][a], tile[5][a], tile[6][a], tile[7][a]};
        *(float4*)(kT + b * (T_ * H_) + a * T_ + s0) = f0;
        *(float4*)(kT + b * (T_ * H_) + a * T_ + s0 + 4) = f1;
    }
}

// ---- logits[b,t,s] = mask ? v . tanh(q[b,t,:]+k[b,s,:]) : -1e9 ----
__global__ __launch_bounds__(256) void k_scores(const float* __restrict__ q,
                                                const float* __restrict__ kT,
                                                const float* __restrict__ v,
                                                const int* __restrict__ pos,
                                                float* __restrict__ out) {
    __shared__ float sq[4][256];
    __shared__ float sv[256];
    int blk = blockIdx.x;
    int b = blk >> 6;
    int t0 = (blk & 63) * 4;
    int s = threadIdx.x;
    sv[s] = v[s];
#pragma unroll
    for (int tt = 0; tt < 4; ++tt)
        sq[tt][s] = q[((b << 8) + t0 + tt) * H_ + s];
    __syncthreads();
    int ps = pos[(b << 8) + s];
    float acc[4] = {0.f, 0.f, 0.f, 0.f};
    const float* kTb = kT + b * (T_ * H_);
    for (int a = 0; a < H_; ++a) {
        float kv = kTb[a * T_ + s];
        float va = sv[a];
#pragma unroll
        for (int tt = 0; tt < 4; ++tt) {
            float th = tanh_f(sq[tt][a] + kv);
            acc[tt] += va * th;
        }
    }
#pragma unroll
    for (int tt = 0; tt < 4; ++tt) {
        int t = t0 + tt;
        out[((b << 8) + t) * T_ + s] = (t <= ps) ? acc[tt] : -1.0e9f;
    }
}

extern "C" void kernel_launch(void* const* d_in, const int* in_sizes, int n_in,
                              void* d_out, int out_size, void* d_ws, size_t ws_size,
                              hipStream_t stream) {
    (void)in_sizes; (void)n_in; (void)out_size; (void)ws_size;
    const float* inputs   = (const float*)d_in[0];
    const int* targets    = (const int*)d_in[1];
    const float* W_enc   = (const float*)d_in[2];
    const float* b_enc   = (const float*)d_in[3];
    const float* enc_Wih = (const float*)d_in[4];
    const float* enc_Whh = (const float*)d_in[5];
    const float* enc_bih = (const float*)d_in[6];
    const float* enc_bhh = (const float*)d_in[7];
    const float* dec_Wih = (const float*)d_in[8];
    const float* dec_Whh = (const float*)d_in[9];
    const float* dec_bih = (const float*)d_in[10];
    const float* dec_bhh = (const float*)d_in[11];
    const float* Wq = (const float*)d_in[12];
    const float* Wk = (const float*)d_in[13];
    const float* v  = (const float*)d_in[14];
    float* out = (float*)d_out;

    float* ws = (float*)d_ws;
    f16x2* giAe    = (f16x2*)ws;                 // 1,048,576 f
    f16*   giBe    = (f16*)(ws + 1048576);       // 524,288 f
    f16x2* giAd    = (f16x2*)(ws + 1572864);     // 1,048,576 f
    f16*   giBd    = (f16*)(ws + 2621440);       // 524,288 f
    float* enc_out = ws + 3145728;               // 1,048,576 f
    float* dec_out = ws + 4194304;               // 1,048,576 f
    int*   w8e     = (int*)(ws + 5242880);       // 49,152 dw
    int*   w8d     = (int*)(ws + 5292032);       // 49,152 dw
    float* sce     = ws + 5341184;               // 768
    float* scd     = ws + 5341952;               // 768
    int*   pos     = (int*)(ws + 5342720);       // 4,096
    float* q  = (float*)giAe;    // alias: gi dead after gru2
    float* kT = (float*)giAd;    // alias

    k_wprep8<<<384, 256, 0, stream>>>(enc_Whh, dec_Whh, w8e, w8d, sce, scd);
    k_pos<<<16, 256, 0, stream>>>(targets, pos);
    k_proj3<<<512, 256, 0, stream>>>(inputs, W_enc, b_enc, enc_Wih, enc_bih, enc_bhh,
                                     nullptr, giAe, giBe);
    k_proj3<<<512, 256, 0, stream>>>(inputs, W_enc, b_enc, dec_Wih, dec_bih, dec_bhh,
                                     targets, giAd, giBd);
    k_gru2<<<16, 512, 0, stream>>>(w8e, w8d, sce, scd, giAe, giBe, giAd, giBd,
                                   enc_bhh, dec_bhh, enc_out, dec_out);
    k_qk<<<1024, 256, 0, stream>>>(dec_out, Wq, enc_out, Wk, q, kT);
    k_scores<<<1024, 256, 0, stream>>>(q, kT, v, pos, out);
}